// Round 9
// baseline (198.902 us; speedup 1.0000x reference)
//
#include <hip/hip_runtime.h>
#include <math.h>

#define DIM    2048
#define BATCH  256
#define PN     56              // PATCH_NUM - MASK_NUM
#define BDIM   (BATCH * DIM)
#define ABLK   2048            // kernel A blocks: B*D/256 columns each -> 8/CU
#define BBLK   1792            // kernel B blocks: x4 waves x2 rows = 14336 rows -> 7/CU
constexpr float KD_T = 4.0f;

// ---------------- reduction helpers (wave = 64) ----------------
__device__ __forceinline__ float wave_sum(float v) {
#pragma unroll
    for (int o = 32; o > 0; o >>= 1) v += __shfl_xor(v, o, 64);
    return v;
}
__device__ __forceinline__ double wave_sum_d(double v) {
#pragma unroll
    for (int o = 32; o > 0; o >>= 1) v += __shfl_xor(v, o, 64);
    return v;
}

// ---------------- kernel A: bar + dil, barrier-free hot loop ----------------
// thread-per-column of flat [B,D]. 56 stride-2MB loads (each wave-instr is a
// coalesced 256B segment), 4 ILP accumulators so loads retire out of order.
// Writes bar (fp32, 2MB, goes through LLC for kernel B) + per-block dil
// 4-tuple. One barrier total (final reduce).
__global__ void __launch_bounds__(256) bar_dil_kernel(const float* __restrict__ ebg,
                                                      const float* __restrict__ ebp,
                                                      float* __restrict__ barw,
                                                      float* __restrict__ pdil)  // [ABLK][4]
{
    __shared__ float red[4][4];
    const int t    = threadIdx.x;
    const int lane = t & 63;
    const int wv   = t >> 6;
    const int idx  = blockIdx.x * 256 + t;          // flat column in [B*D)
    const float invT = 1.0f / KD_T;

    const float* p0 = ebp + idx;
    float a0 = 0.f, a1 = 0.f, a2 = 0.f, a3 = 0.f;
#pragma unroll
    for (int p = 0; p < PN; p += 4) {
        a0 += p0[(size_t)(p + 0) * BDIM];
        a1 += p0[(size_t)(p + 1) * BDIM];
        a2 += p0[(size_t)(p + 2) * BDIM];
        a3 += p0[(size_t)(p + 3) * BDIM];
    }
    const float bar = (a0 + a1 + a2 + a3) * (1.0f / PN);
    barw[idx] = bar;

    // dil partial at this column: s=g/T, tv=bar/T (sym-KL one-pass terms)
    const float g  = ebg[idx];
    const float s  = g * invT, tv = bar * invT;
    const float es = __expf(s), et = __expf(tv);
    const float dd = tv - s;
    float dss = es, dts = et, dt1 = es * dd, dt2 = et * dd;

    dss = wave_sum(dss); dts = wave_sum(dts);
    dt1 = wave_sum(dt1); dt2 = wave_sum(dt2);
    if (lane == 0) { red[wv][0] = dss; red[wv][1] = dts; red[wv][2] = dt1; red[wv][3] = dt2; }
    __syncthreads();
    if (t == 0) {
        float* qp = pdil + (size_t)blockIdx.x * 4;
#pragma unroll
        for (int k = 0; k < 4; ++k)
            qp[k] = red[0][k] + red[1][k] + red[2][k] + red[3][k];
    }
}

// ---------------- kernel B: dcl, wave-per-row, barrier-free hot loop --------
// wave gw owns rows 2*gw, 2*gw+1 (consecutive rows are contiguous in ebp ->
// each wave streams 16KB sequentially; ebp is LLC-warm from kernel A).
// ebg/barw rows (2MB each) are L2/LLC-served. One barrier total.
__global__ void __launch_bounds__(256) dcl_kernel(const float* __restrict__ ebg,
                                                  const float* __restrict__ barw,
                                                  const float* __restrict__ ebp,
                                                  double* __restrict__ pdcl)   // [BBLK]
{
    __shared__ double sd[4];
    const int t    = threadIdx.x;
    const int lane = t & 63;
    const int wv   = t >> 6;
    const int gw   = blockIdx.x * 4 + wv;
    const float invT = 1.0f / KD_T;

    double dacc = 0.0;
#pragma unroll
    for (int rr = 0; rr < 2; ++rr) {
        const int row = gw * 2 + rr;                 // 0..14335, = p*BATCH + b
        const int b   = row & (BATCH - 1);
        const float4* e4 = (const float4*)(ebp  + (size_t)row * DIM);
        const float4* g4 = (const float4*)(ebg  + (size_t)b   * DIM);
        const float4* m4 = (const float4*)(barw + (size_t)b   * DIM);

        float asum = 0.f, csum = 0.f, t1 = 0.f, t2 = 0.f;
#pragma unroll
        for (int j = 0; j < 8; ++j) {
            float4 e = e4[j * 64 + lane];
            float4 g = g4[j * 64 + lane];
            float4 m = m4[j * 64 + lane];
            float es_[4] = {e.x, e.y, e.z, e.w};
            float gs[4]  = {g.x, g.y, g.z, g.w};
            float ms[4]  = {m.x, m.y, m.z, m.w};
#pragma unroll
            for (int k = 0; k < 4; ++k) {
                float dg = gs[k] - es_[k];
                float db = ms[k] - es_[k];
                float a   = dg * dg * invT;
                float cc2 = db * db * invT;
                float ea = __expf(a), ec = __expf(cc2);
                float d  = cc2 - a;
                asum += ea; csum += ec;
                t1 = fmaf(ea, d, t1);
                t2 = fmaf(ec, d, t2);
            }
        }
        asum = wave_sum(asum); csum = wave_sum(csum);
        t1 = wave_sum(t1);     t2 = wave_sum(t2);
        dacc += (double)(t2 / csum - t1 / asum);
    }
    if (lane == 0) sd[wv] = dacc;
    __syncthreads();
    if (t == 0) pdcl[blockIdx.x] = sd[0] + sd[1] + sd[2] + sd[3];
}

// ---------------- finalize: combine partials, emit 2 outputs ----------------
__global__ void __launch_bounds__(256) finalize_kernel(const double* __restrict__ pdcl,
                                                       const float* __restrict__ pdil,
                                                       float* __restrict__ out)
{
    __shared__ double sdc[4], sdl[4];
    const int t = threadIdx.x, lane = t & 63, wv = t >> 6;

    // dcl: sum BBLK per-block doubles (7 each)
    double vd = 0.0;
    for (int i = t; i < BBLK; i += 256) vd += pdcl[i];

    // dil: thread t owns b=t; its 8 column-slices are blocks b*8..b*8+7
    const float* base = pdil + (size_t)t * 8 * 4;
    double ss = 0.0, ts = 0.0, u1 = 0.0, u2 = 0.0;
#pragma unroll
    for (int k = 0; k < 8; ++k) {
        float4 v = *(const float4*)(base + k * 4);
        ss += v.x; ts += v.y; u1 += v.z; u2 += v.w;
    }
    double vl = u2 / ts - u1 / ss;

    vd = wave_sum_d(vd); vl = wave_sum_d(vl);
    if (lane == 0) { sdc[wv] = vd; sdl[wv] = vl; }
    __syncthreads();
    if (t == 0) {
        const double kT2 = (double)KD_T * KD_T;
        out[0] = (float)((sdl[0] + sdl[1] + sdl[2] + sdl[3]) * (kT2 / DIM));
        out[1] = (float)((sdc[0] + sdc[1] + sdc[2] + sdc[3]) * (kT2 / DIM / PN));
    }
}

extern "C" void kernel_launch(void* const* d_in, const int* in_sizes, int n_in,
                              void* d_out, int out_size, void* d_ws, size_t ws_size,
                              hipStream_t stream) {
    const float* ebg = (const float*)d_in[0];
    const float* ebp = (const float*)d_in[1];
    // labels (d_in[2]) unused by the forward computation

    float*  barw = (float*)d_ws;                            // [B,D] fp32, 2 MB
    float*  pdil = barw + (size_t)BATCH * DIM;              // ABLK*4 floats = 32 KB
    double* pdcl = (double*)(pdil + (size_t)ABLK * 4);      // BBLK doubles = 14 KB

    bar_dil_kernel<<<ABLK, 256, 0, stream>>>(ebg, ebp, barw, pdil);
    dcl_kernel<<<BBLK, 256, 0, stream>>>(ebg, barw, ebp, pdcl);
    finalize_kernel<<<1, 256, 0, stream>>>(pdcl, pdil, (float*)d_out);
}